// Round 9
// baseline (225.377 us; speedup 1.0000x reference)
//
#include <hip/hip_runtime.h>

// MultiHeadAttention: B=2,S=2048,D=768,H=12,depth=64. fp32 in/out, bf16 MFMA inside.
// R9 = R8 with the attn loadKV units bug fixed (element offsets, not tile index).
// All-register prefetch staging; convert fused into gemm_qkv; lsum fused into
// gemm_out. 4 dispatches: Wt transpose -> QKV gemm -> flash attn -> out gemm.

typedef __bf16 bf16;
typedef __bf16 bf16x8 __attribute__((ext_vector_type(8)));
typedef __bf16 bf16x4 __attribute__((ext_vector_type(4)));
typedef float  f32x4  __attribute__((ext_vector_type(4)));

// chunk table: (qt | c<<4), descending tile count (long blocks dispatch first)
__constant__ unsigned char chunk_tab[40] = {
  3, 4, 5, 6, 7, 8, 9, 10, 11, 12, 13, 14, 15,
  7 | 16, 8 | 16, 9 | 16, 10 | 16, 11 | 16, 12 | 16, 13 | 16, 14 | 16, 15 | 16,
  11 | 32, 12 | 32, 13 | 32, 14 | 32, 15 | 32,
  15 | 48,
  2, 6 | 16, 10 | 32, 14 | 48,
  1, 5 | 16, 9 | 32, 13 | 48,
  0, 4 | 16, 8 | 32, 12 | 48,
};

// ---------------- prep: W fp32 [k][n] -> bf16 Wt [n][k] ----------------
__global__ __launch_bounds__(256) void transpose_w_kernel(
    const float* __restrict__ W0, const float* __restrict__ W1,
    const float* __restrict__ W2, const float* __restrict__ W3,
    bf16* __restrict__ T0, bf16* __restrict__ T1,
    bf16* __restrict__ T2, bf16* __restrict__ T3) {
  const float* W; bf16* T;
  switch (blockIdx.z) {
    case 0: W = W0; T = T0; break;
    case 1: W = W1; T = T1; break;
    case 2: W = W2; T = T2; break;
    default: W = W3; T = T3; break;
  }
  __shared__ float tile[32][33];
  const int tx = threadIdx.x, ty = threadIdx.y;   // 32 x 8
  const int k0 = blockIdx.y * 32, n0 = blockIdx.x * 32;
#pragma unroll
  for (int j = 0; j < 32; j += 8)
    tile[ty + j][tx] = W[(size_t)(k0 + ty + j) * 768 + n0 + tx];
  __syncthreads();
#pragma unroll
  for (int j = 0; j < 32; j += 8) {
    int n = ty + j;
    T[(size_t)(n0 + n) * 768 + k0 + tx] = (bf16)tile[tx][n];
  }
}

// ---------------- QKV GEMM: C[128x128] = X_fp32[m][k] * Wt[n][k]^T + bias ----------
// Fused fp32->bf16 convert in A staging. All operands register-prefetched one
// K-iteration ahead; single 32KB LDS buffer; 576 blocks XCD-swizzled.
__global__ __launch_bounds__(256, 3) void gemm_qkv_kernel(
    const float* __restrict__ X0, const float* __restrict__ X1, const float* __restrict__ X2,
    const bf16* __restrict__ W0, const bf16* __restrict__ W1, const bf16* __restrict__ W2,
    const float* __restrict__ b0, const float* __restrict__ b1, const float* __restrict__ b2,
    bf16* __restrict__ Q, bf16* __restrict__ K, bf16* __restrict__ V) {
  __shared__ __align__(16) char smem[32768];
  const int bidx = blockIdx.x;
  const int xcd = bidx & 7, ii = bidx >> 3;   // ii 0..71
  const int nt = ii % 6, mzi = ii / 6;        // mzi 0..11
  const int mz = mzi * 8 + xcd;               // 0..95
  const int m = mz & 31, z = mz >> 5;
  const int m0 = m * 128, n0 = nt * 128;

  const float* A    = (z == 0) ? X0 : (z == 1) ? X1 : X2;
  const bf16* Wt    = (z == 0) ? W0 : (z == 1) ? W1 : W2;
  const float* bias = (z == 0) ? b0 : (z == 1) ? b1 : b2;
  bf16* outb = (z == 0) ? Q : (z == 1) ? K : V;
  const int mode = (z == 2) ? 1 : 0;

  const int t = threadIdx.x;
  const int w = t >> 6, lane = t & 63;
  const int wm = w >> 1, wn = w & 1;
  const int quad = lane >> 4, l15 = lane & 15;
  const int srow = lane >> 3, k8p = lane & 7;

  // B: bf16 reg staging (same per-lane addressing the DMA used)
  size_t offB[4]; int ldsB[4];   // element index into smem (bf16)
#pragma unroll
  for (int i = 0; i < 4; ++i) {
    const int rl = w * 32 + i * 8 + srow;
    const int kk = k8p ^ (rl & 7);
    offB[i] = (size_t)(n0 + rl) * 768 + kk * 8;
    ldsB[i] = 8192 + (w * 32 + i * 8) * 64 + lane * 8;
  }
  // A: fp32 reg staging (fused convert)
  const int arow0 = t >> 3;   // 0..31
  const int ac = t & 7;
  size_t offA[4]; int aposA[4];
#pragma unroll
  for (int i = 0; i < 4; ++i) {
    const int row = arow0 + i * 32;
    offA[i] = (size_t)(m0 + row) * 768 + ac * 8;
    aposA[i] = row * 64 + ((ac ^ (row & 7)) << 3);
  }

  f32x4 acc[4][4] = {};
  f32x4 pa[4], pb[4];
  bf16x8 pw[4];

  auto loadAB = [&](int k1) {
#pragma unroll
    for (int i = 0; i < 4; ++i) {
      pa[i] = *(const f32x4*)(A + offA[i] + k1);
      pb[i] = *(const f32x4*)(A + offA[i] + k1 + 4);
    }
#pragma unroll
    for (int i = 0; i < 4; ++i)
      pw[i] = *(const bf16x8*)(Wt + offB[i] + k1);
  };
  auto writeAB = [&]() {
    bf16* As = (bf16*)smem;
#pragma unroll
    for (int i = 0; i < 4; ++i) {
      bf16x8 o;
      o[0]=(bf16)pa[i][0]; o[1]=(bf16)pa[i][1]; o[2]=(bf16)pa[i][2]; o[3]=(bf16)pa[i][3];
      o[4]=(bf16)pb[i][0]; o[5]=(bf16)pb[i][1]; o[6]=(bf16)pb[i][2]; o[7]=(bf16)pb[i][3];
      *(bf16x8*)(As + aposA[i]) = o;
      *(bf16x8*)(As + ldsB[i]) = pw[i];
    }
  };

  loadAB(0);
  for (int kidx = 0; kidx < 12; ++kidx) {
    writeAB();                      // consumes loads issued one iteration ago
    __syncthreads();
    if (kidx < 11) loadAB((kidx + 1) * 64);   // register prefetch (element offset)
    const bf16* As = (const bf16*)smem;
    const bf16* Bs = (const bf16*)smem + 8192;
#pragma unroll
    for (int ks = 0; ks < 2; ++ks) {
      bf16x8 af[4], bfv[4];
      const int slot = (((ks * 4 + quad) ^ (lane & 7)) * 8);
#pragma unroll
      for (int mi = 0; mi < 4; ++mi)
        af[mi] = *(const bf16x8*)(As + (wm * 64 + mi * 16 + l15) * 64 + slot);
#pragma unroll
      for (int ni = 0; ni < 4; ++ni)
        bfv[ni] = *(const bf16x8*)(Bs + (wn * 64 + ni * 16 + l15) * 64 + slot);
#pragma unroll
      for (int mi = 0; mi < 4; ++mi)
#pragma unroll
        for (int ni = 0; ni < 4; ++ni)
          acc[mi][ni] = __builtin_amdgcn_mfma_f32_16x16x32_bf16(af[mi], bfv[ni], acc[mi][ni], 0, 0, 0);
    }
    __syncthreads();
  }

#pragma unroll
  for (int ni = 0; ni < 4; ++ni) {
    const float bc = bias[n0 + wn * 64 + ni * 16 + l15];
#pragma unroll
    for (int mi = 0; mi < 4; ++mi)
#pragma unroll
      for (int r = 0; r < 4; ++r) acc[mi][ni][r] += bc;
  }

  // epilogue in two 64-row halves
  if (mode == 0) {
    bf16* Ce = (bf16*)smem;
#pragma unroll
    for (int hh = 0; hh < 2; ++hh) {
      if (wm == hh) {
#pragma unroll
        for (int ni = 0; ni < 4; ++ni) {
          const int col = wn * 64 + ni * 16 + l15;
#pragma unroll
          for (int mi = 0; mi < 4; ++mi) {
            const int row = mi * 16 + quad * 4;
#pragma unroll
            for (int r = 0; r < 4; ++r)
              Ce[(row + r) * 136 + col] = (bf16)acc[mi][ni][r];
          }
        }
      }
      __syncthreads();
#pragma unroll
      for (int j = 0; j < 4; ++j) {
        const int ci = j * 256 + t;
        const int row = ci >> 4, c8 = (ci & 15) * 8;
        bf16x8 vv = *(const bf16x8*)(Ce + row * 136 + c8);
        const int rg = m0 + hh * 64 + row, cg = n0 + c8;
        const int bb = rg >> 11, s = rg & 2047;
        const int h = cg >> 6, d = cg & 63;
        *(bf16x8*)(outb + ((size_t)(bb * 12 + h) * 2048 + s) * 64 + d) = vv;
      }
      __syncthreads();
    }
  } else {
    bf16* Ct = (bf16*)smem;   // [col 128][row 64+pad], stride 72
#pragma unroll
    for (int hh = 0; hh < 2; ++hh) {
      if (wm == hh) {
#pragma unroll
        for (int ni = 0; ni < 4; ++ni) {
          const int col = wn * 64 + ni * 16 + l15;
#pragma unroll
          for (int mi = 0; mi < 4; ++mi) {
            const int row = mi * 16 + quad * 4;
            bf16x4 pv;
            pv[0] = (bf16)acc[mi][ni][0]; pv[1] = (bf16)acc[mi][ni][1];
            pv[2] = (bf16)acc[mi][ni][2]; pv[3] = (bf16)acc[mi][ni][3];
            *(bf16x4*)(Ct + (size_t)col * 72 + row) = pv;
          }
        }
      }
      __syncthreads();
#pragma unroll
      for (int j = 0; j < 4; ++j) {
        const int ci = j * 256 + t;
        const int col = ci >> 3, r8 = (ci & 7) * 8;
        bf16x8 vv = *(const bf16x8*)(Ct + col * 72 + r8);
        const int cg = n0 + col;
        const int h = cg >> 6, d = cg & 63;
        const int rg = m0 + hh * 64 + r8;
        const int bb = rg >> 11, s = rg & 2047;
        *(bf16x8*)(outb + ((size_t)(bb * 12 + h) * 64 + d) * 2048 + s) = vv;
      }
      __syncthreads();
    }
  }
}

// ---------------- flash attention, 4-way split-K, reg-prefetched K/V ----------------
__global__ __launch_bounds__(256, 4) void attn_kernel(
    const bf16* __restrict__ Qh, const bf16* __restrict__ Kh,
    const bf16* __restrict__ Vt,
    bf16* __restrict__ O0, bf16* __restrict__ O1,
    bf16* __restrict__ O2, bf16* __restrict__ O3,
    float* __restrict__ L0, float* __restrict__ L1,
    float* __restrict__ L2, float* __restrict__ L3) {
  const int ent = chunk_tab[blockIdx.x / 24];
  const int bh = blockIdx.x % 24;
  const int qt = ent & 15, c = ent >> 4;
  const int q0 = qt * 128;
  const int kt_begin = c * 8;
  const int ntiles = 2 * qt + 2;
  const int kt_end = (kt_begin + 8 < ntiles) ? kt_begin + 8 : ntiles;

  __shared__ __align__(16) char smem[32768];
  bf16* Ps = (bf16*)(smem + 16384);   // [128 q][64 key] swizzled (wave-private rows)

  const int t = threadIdx.x;
  const int w = t >> 6, lane = t & 63, quad = lane >> 4, l15 = lane & 15;
  const int srow = lane >> 3, k8p = lane & 7;
  const bf16* Qp = Qh + (size_t)bh * (2048 * 64);
  const bf16* Kp = Kh + (size_t)bh * (2048 * 64);
  const bf16* Vp = Vt + (size_t)bh * (64 * 2048);

  size_t offK[2], offV[2];
  int ldsK[2], ldsV[2];   // element index
#pragma unroll
  for (int i = 0; i < 2; ++i) {
    const int rl = w * 16 + i * 8 + srow;
    const int kk = k8p ^ (rl & 7);
    offK[i] = (size_t)rl * 64 + kk * 8;
    offV[i] = (size_t)rl * 2048 + kk * 8;
    ldsK[i] = (w * 16 + i * 8) * 64 + lane * 8;
    ldsV[i] = 4096 + (w * 16 + i * 8) * 64 + lane * 8;
  }

  bf16x8 qf[2][2];
#pragma unroll
  for (int mi = 0; mi < 2; ++mi)
#pragma unroll
    for (int ks = 0; ks < 2; ++ks) {
      const int qrow = q0 + w * 32 + mi * 16 + l15;
      qf[mi][ks] = *(const bf16x8*)(Qp + (size_t)qrow * 64 + ks * 32 + quad * 8);
    }

  f32x4 o[2][4] = {};
  float lp[2] = {0.f, 0.f};
  const float sc = 0.125f * 1.44269504f;

  bf16x8 kreg[2], vreg[2];
  // kb = element row base of the tile (kt*64). K: +kb*64 (row stride 64);
  // V: +kb (column offset into [64][2048]).
  auto loadKV = [&](int kb) {
#pragma unroll
    for (int i = 0; i < 2; ++i) {
      kreg[i] = *(const bf16x8*)(Kp + offK[i] + (size_t)kb * 64);
      vreg[i] = *(const bf16x8*)(Vp + offV[i] + kb);
    }
  };

  loadKV(kt_begin * 64);
  for (int kt = kt_begin; kt < kt_end; ++kt) {
    const int k0 = kt * 64;
    bf16* sw = (bf16*)smem;
#pragma unroll
    for (int i = 0; i < 2; ++i) {
      *(bf16x8*)(sw + ldsK[i]) = kreg[i];
      *(bf16x8*)(sw + ldsV[i]) = vreg[i];
    }
    __syncthreads();
    if (kt + 1 < kt_end) loadKV((kt + 1) * 64);   // register prefetch
    const bf16* Ks = (const bf16*)smem;
    const bf16* Vs = (const bf16*)smem + 4096;

    // S^T = K Q^T : col = q (l15), row = key (ni*16+quad*4+r)
    f32x4 st[4][2] = {};
#pragma unroll
    for (int ks = 0; ks < 2; ++ks) {
      const int slot = (((ks * 4 + quad) ^ (lane & 7)) * 8);
      bf16x8 kf[4];
#pragma unroll
      for (int ni = 0; ni < 4; ++ni)
        kf[ni] = *(const bf16x8*)(Ks + (ni * 16 + l15) * 64 + slot);
#pragma unroll
      for (int ni = 0; ni < 4; ++ni)
#pragma unroll
        for (int mi = 0; mi < 2; ++mi)
          st[ni][mi] = __builtin_amdgcn_mfma_f32_16x16x32_bf16(kf[ni], qf[mi][ks], st[ni][mi], 0, 0, 0);
    }

    const bool diag = (k0 + 63 > q0);
#pragma unroll
    for (int mi = 0; mi < 2; ++mi) {
      const int q_local = w * 32 + mi * 16 + l15;
      const int qg = q0 + q_local;
#pragma unroll
      for (int ni = 0; ni < 4; ++ni) {
        bf16x4 pv;
#pragma unroll
        for (int r = 0; r < 4; ++r) {
          float p = __builtin_amdgcn_exp2f(st[ni][mi][r] * sc);
          if (diag && (k0 + ni * 16 + quad * 4 + r > qg)) p = 0.0f;
          lp[mi] += p;
          pv[r] = (bf16)p;
        }
        const int cc = ni * 2 + (quad >> 1);
        *(bf16x4*)(Ps + q_local * 64 + ((cc ^ (q_local & 7)) << 3) + ((quad & 1) << 2)) = pv;
      }
    }

#pragma unroll
    for (int ks = 0; ks < 2; ++ks) {
      const int slot = (((ks * 4 + quad) ^ (lane & 7)) * 8);
      bf16x8 pf[2], vfr[4];
#pragma unroll
      for (int mi = 0; mi < 2; ++mi)
        pf[mi] = *(const bf16x8*)(Ps + (w * 32 + mi * 16 + l15) * 64 + slot);
#pragma unroll
      for (int di = 0; di < 4; ++di)
        vfr[di] = *(const bf16x8*)(Vs + (di * 16 + l15) * 64 + slot);
#pragma unroll
      for (int mi = 0; mi < 2; ++mi)
#pragma unroll
        for (int di = 0; di < 4; ++di)
          o[mi][di] = __builtin_amdgcn_mfma_f32_16x16x32_bf16(pf[mi], vfr[di], o[mi][di], 0, 0, 0);
    }
    __syncthreads();
  }

  bf16* Op; float* Lp_;
  switch (c) {
    case 0: Op = O0; Lp_ = L0; break;
    case 1: Op = O1; Lp_ = L1; break;
    case 2: Op = O2; Lp_ = L2; break;
    default: Op = O3; Lp_ = L3; break;
  }
  const int rows_c = 2048 - 512 * c;
  const size_t rbase = (size_t)bh * rows_c + (q0 - 512 * c);

#pragma unroll
  for (int mi = 0; mi < 2; ++mi) {
    float l = lp[mi];
    l += __shfl_xor(l, 16);
    l += __shfl_xor(l, 32);
    if (quad == 0) Lp_[rbase + w * 32 + mi * 16 + l15] = l;
#pragma unroll
    for (int di = 0; di < 4; ++di) {
      const int d = di * 16 + l15;
#pragma unroll
      for (int r = 0; r < 4; ++r) {
        const size_t row = rbase + w * 32 + mi * 16 + quad * 4 + r;
        Op[row * 64 + d] = (bf16)o[mi][di][r];
      }
    }
  }
}

// ---------------- out GEMM (fused combine+normalize+lsum) ----------------
// 64-row m-tiles, 384 blocks XCD-swizzled. Linv computed per-block into LDS.
// A (split-K partial sums) and B both register-prefetched; 24KB+3KB LDS.
__global__ __launch_bounds__(256, 4) void gemm_out_kernel(
    const bf16* __restrict__ O0, const bf16* __restrict__ O1,
    const bf16* __restrict__ O2, const bf16* __restrict__ O3,
    const float* __restrict__ L0, const float* __restrict__ L1,
    const float* __restrict__ L2, const float* __restrict__ L3,
    const bf16* __restrict__ Wt, const float* __restrict__ bias,
    float* __restrict__ out) {
  __shared__ __align__(16) char smem[27648];   // As 8KB@0, Bs 16KB@8192, LivS 3KB@24576
  float* LivS = (float*)(smem + 24576);        // [12 heads][64 rows]
  const int bidx = blockIdx.x;                 // 384
  const int xcd = bidx & 7, ii = bidx >> 3;    // ii 0..47
  const int nt = ii % 6, mg = ii / 6;          // mg 0..7
  const int mt = mg * 8 + xcd;                 // 0..63
  const int m0 = mt * 64, n0 = nt * 128;
  const int bb = mt >> 5;                      // batch
  const int s0 = (mt & 31) * 64;               // 0..1984
  const int nch = 1 + (s0 >= 512) + (s0 >= 1024) + (s0 >= 1536);

  const int t = threadIdx.x;
  const int w = t >> 6, lane = t & 63;
  const int wm = w >> 1, wn = w & 1;
  const int quad = lane >> 4, l15 = lane & 15;
  const int srow = lane >> 3, k8p = lane & 7;

  // per-block Linv into LDS
  for (int idx = t; idx < 768; idx += 256) {
    const int kk = idx >> 6, r = idx & 63;
    const int s = s0 + r;
    const size_t bh = (size_t)(bb * 12 + kk);
    float l = L0[bh * 2048 + s];
    if (s >= 512)  l += L1[bh * 1536 + (s - 512)];
    if (s >= 1024) l += L2[bh * 1024 + (s - 1024)];
    if (s >= 1536) l += L3[bh * 512  + (s - 1536)];
    LivS[idx] = 1.0f / l;
  }

  size_t offB[4]; int ldsB[4];
#pragma unroll
  for (int i = 0; i < 4; ++i) {
    const int rl = w * 32 + i * 8 + srow;
    const int kk = k8p ^ (rl & 7);
    offB[i] = (size_t)(n0 + rl) * 768 + kk * 8;
    ldsB[i] = 4096 + (w * 32 + i * 8) * 64 + lane * 8;
  }
  const int arow = t >> 2;       // 0..63
  const int ac2 = (t & 3) * 2;
  const int sA = s0 + arow;
  size_t ro0[2], ro1[2], ro2[2], ro3[2];
  int aposA[2];
#pragma unroll
  for (int j = 0; j < 2; ++j) {
    const int cch = ac2 + j;
    ro0[j] = (size_t)sA * 64 + cch * 8;
    ro1[j] = (size_t)(sA - 512) * 64 + cch * 8;
    ro2[j] = (size_t)(sA - 1024) * 64 + cch * 8;
    ro3[j] = (size_t)(sA - 1536) * 64 + cch * 8;
    aposA[j] = arow * 64 + ((cch ^ (arow & 7)) << 3);
  }

  f32x4 acc[2][4] = {};
  bf16x8 pa0[2], pa1[2], pa2[2], pa3[2], pw[4];
  int kkcur = 0;

  auto loadAB = [&](int kk) {
    kkcur = kk;
    const size_t bh = (size_t)(bb * 12 + kk);
#pragma unroll
    for (int j = 0; j < 2; ++j) pa0[j] = *(const bf16x8*)(O0 + bh * 131072 + ro0[j]);
    if (nch >= 2)
#pragma unroll
      for (int j = 0; j < 2; ++j) pa1[j] = *(const bf16x8*)(O1 + bh * 98304 + ro1[j]);
    if (nch >= 3)
#pragma unroll
      for (int j = 0; j < 2; ++j) pa2[j] = *(const bf16x8*)(O2 + bh * 65536 + ro2[j]);
    if (nch >= 4)
#pragma unroll
      for (int j = 0; j < 2; ++j) pa3[j] = *(const bf16x8*)(O3 + bh * 32768 + ro3[j]);
#pragma unroll
    for (int i = 0; i < 4; ++i)
      pw[i] = *(const bf16x8*)(Wt + offB[i] + kk * 64);
  };
  auto writeAB = [&]() {
    bf16* As = (bf16*)smem;
    const float lv = LivS[kkcur * 64 + arow];
#pragma unroll
    for (int j = 0; j < 2; ++j) {
      float f[8];
#pragma unroll
      for (int k = 0; k < 8; ++k) f[k] = (float)pa0[j][k];
      if (nch >= 2)
#pragma unroll
        for (int k = 0; k < 8; ++k) f[k] += (float)pa1[j][k];
      if (nch >= 3)
#pragma unroll
        for (int k = 0; k < 8; ++k) f[k] += (float)pa2[j][k];
      if (nch >= 4)
#pragma unroll
        for (int k = 0; k < 8; ++k) f[k] += (float)pa3[j][k];
      bf16x8 o;
#pragma unroll
      for (int k = 0; k < 8; ++k) o[k] = (bf16)(f[k] * lv);
      *(bf16x8*)(As + aposA[j]) = o;
    }
#pragma unroll
    for (int i = 0; i < 4; ++i)
      *(bf16x8*)(As + ldsB[i]) = pw[i];
  };

  loadAB(0);
  __syncthreads();   // LivS visible before first writeAB reads it
  for (int kidx = 0; kidx < 12; ++kidx) {
    writeAB();
    __syncthreads();
    if (kidx < 11) loadAB(kidx + 1);
    const bf16* As = (const bf16*)smem;
    const bf16* Bs = (const bf16*)smem + 4096;
#pragma unroll
    for (int ks = 0; ks < 2; ++ks) {
      bf16x8 af[2], bfv[4];
      const int slot = (((ks * 4 + quad) ^ (lane & 7)) * 8);
#pragma unroll
      for (int mi = 0; mi < 2; ++mi)
        af[mi] = *(const bf16x8*)(As + (wm * 32 + mi * 16 + l15) * 64 + slot);
#pragma unroll
      for (int ni = 0; ni < 4; ++ni)
        bfv[ni] = *(const bf16x8*)(Bs + (wn * 64 + ni * 16 + l15) * 64 + slot);
#pragma unroll
      for (int mi = 0; mi < 2; ++mi)
#pragma unroll
        for (int ni = 0; ni < 4; ++ni)
          acc[mi][ni] = __builtin_amdgcn_mfma_f32_16x16x32_bf16(af[mi], bfv[ni], acc[mi][ni], 0, 0, 0);
    }
    __syncthreads();
  }

#pragma unroll
  for (int ni = 0; ni < 4; ++ni) {
    const float bc = bias[n0 + wn * 64 + ni * 16 + l15];
#pragma unroll
    for (int mi = 0; mi < 2; ++mi)
#pragma unroll
      for (int r = 0; r < 4; ++r) acc[mi][ni][r] += bc;
  }

#pragma unroll
  for (int ni = 0; ni < 4; ++ni) {
    const int col = n0 + wn * 64 + ni * 16 + l15;
#pragma unroll
    for (int mi = 0; mi < 2; ++mi) {
      const int row = m0 + wm * 32 + mi * 16 + quad * 4;
#pragma unroll
      for (int r = 0; r < 4; ++r)
        out[(size_t)(row + r) * 768 + col] = acc[mi][ni][r];
    }
  }
}

extern "C" void kernel_launch(void* const* d_in, const int* in_sizes, int n_in,
                              void* d_out, int out_size, void* d_ws, size_t ws_size,
                              hipStream_t stream) {
  const float* query = (const float*)d_in[0];
  const float* key   = (const float*)d_in[1];
  const float* value = (const float*)d_in[2];
  // d_in[3] = mask (causal triu, implemented analytically)
  const float* Wq = (const float*)d_in[4];
  const float* bq = (const float*)d_in[5];
  const float* Wk = (const float*)d_in[6];
  const float* bk = (const float*)d_in[7];
  const float* Wv = (const float*)d_in[8];
  const float* bv = (const float*)d_in[9];
  const float* Wo = (const float*)d_in[10];
  const float* bo = (const float*)d_in[11];
  float* out = (float*)d_out;

  char* ws = (char*)d_ws;
  bf16* O0   = (bf16*)(ws);              // 24*2048*64 bf16
  bf16* O1   = (bf16*)(ws + 6291456);    // 24*1536*64
  bf16* O2   = (bf16*)(ws + 11010048);   // 24*1024*64
  bf16* O3   = (bf16*)(ws + 14155776);   // 24*512*64
  float* L0  = (float*)(ws + 15728640);  // 24*2048 f32
  float* L1  = (float*)(ws + 15925248);
  float* L2  = (float*)(ws + 16072704);
  float* L3  = (float*)(ws + 16171008);
  bf16* wtq  = (bf16*)(ws + 16220160);
  bf16* wtk  = (bf16*)(ws + 17399808);
  bf16* wtv  = (bf16*)(ws + 18579456);
  bf16* wto  = (bf16*)(ws + 19759104);
  bf16* Qh   = (bf16*)(ws + 20938752);
  bf16* Kh   = (bf16*)(ws + 27230208);
  bf16* Vtb  = (bf16*)(ws + 33521664);   // ends 39813120 (~38 MB)

  transpose_w_kernel<<<dim3(24, 24, 4), dim3(32, 8), 0, stream>>>(Wq, Wk, Wv, Wo, wtq, wtk, wtv, wto);
  gemm_qkv_kernel<<<dim3(576), 256, 0, stream>>>(query, key, value, wtq, wtk, wtv, bq, bk, bv, Qh, Kh, Vtb);
  attn_kernel<<<dim3(960), 256, 0, stream>>>(Qh, Kh, Vtb, O0, O1, O2, O3, L0, L1, L2, L3);
  gemm_out_kernel<<<dim3(384), 256, 0, stream>>>(O0, O1, O2, O3, L0, L1, L2, L3, wto, bo, out);
}

// Round 10
// 192.978 us; speedup vs baseline: 1.1679x; 1.1679x over previous
//
#include <hip/hip_runtime.h>

// MultiHeadAttention: B=2,S=2048,D=768,H=12,depth=64. fp32 in/out, bf16 MFMA inside.
// R10 = R7 structure (proven 189us) + coalesced attn O-partial epilogue (LDS
// transpose -> bf16x8 stores; R9 showed 134MB WRITE from scalar 2B stores).
// convert -> Wt transpose -> QKV gemm -> flash attn (4-way split-K) -> lsum -> out gemm.

typedef __bf16 bf16;
typedef __bf16 bf16x8 __attribute__((ext_vector_type(8)));
typedef __bf16 bf16x4 __attribute__((ext_vector_type(4)));
typedef float  f32x4  __attribute__((ext_vector_type(4)));

__device__ __forceinline__ void async_load16(const void* g, void* l) {
  __builtin_amdgcn_global_load_lds(
      (__attribute__((address_space(1))) void*)g,
      (__attribute__((address_space(3))) void*)l, 16, 0, 0);
}

// chunk table: (qt | c<<4), descending tile count (long blocks dispatch first)
__constant__ unsigned char chunk_tab[40] = {
  3, 4, 5, 6, 7, 8, 9, 10, 11, 12, 13, 14, 15,
  7 | 16, 8 | 16, 9 | 16, 10 | 16, 11 | 16, 12 | 16, 13 | 16, 14 | 16, 15 | 16,
  11 | 32, 12 | 32, 13 | 32, 14 | 32, 15 | 32,
  15 | 48,
  2, 6 | 16, 10 | 32, 14 | 48,
  1, 5 | 16, 9 | 32, 13 | 48,
  0, 4 | 16, 8 | 32, 12 | 48,
};

// ---------------- prep: fp32 -> bf16 convert (q,k,v) ----------------
__global__ __launch_bounds__(256) void convert_kernel(
    const float* __restrict__ q, const float* __restrict__ k,
    const float* __restrict__ v, bf16* __restrict__ qo,
    bf16* __restrict__ ko, bf16* __restrict__ vo) {
  const float* src; bf16* dst;
  if (blockIdx.y == 0)      { src = q; dst = qo; }
  else if (blockIdx.y == 1) { src = k; dst = ko; }
  else                      { src = v; dst = vo; }
  size_t i = ((size_t)blockIdx.x * 256 + threadIdx.x) * 8;
  f32x4 a = *(const f32x4*)(src + i);
  f32x4 b = *(const f32x4*)(src + i + 4);
  bf16x8 o;
  o[0]=(bf16)a[0]; o[1]=(bf16)a[1]; o[2]=(bf16)a[2]; o[3]=(bf16)a[3];
  o[4]=(bf16)b[0]; o[5]=(bf16)b[1]; o[6]=(bf16)b[2]; o[7]=(bf16)b[3];
  *(bf16x8*)(dst + i) = o;
}

// ---------------- prep: W fp32 [k][n] -> bf16 Wt [n][k] ----------------
__global__ __launch_bounds__(256) void transpose_w_kernel(
    const float* __restrict__ W0, const float* __restrict__ W1,
    const float* __restrict__ W2, const float* __restrict__ W3,
    bf16* __restrict__ T0, bf16* __restrict__ T1,
    bf16* __restrict__ T2, bf16* __restrict__ T3) {
  const float* W; bf16* T;
  switch (blockIdx.z) {
    case 0: W = W0; T = T0; break;
    case 1: W = W1; T = T1; break;
    case 2: W = W2; T = T2; break;
    default: W = W3; T = T3; break;
  }
  __shared__ float tile[32][33];
  const int tx = threadIdx.x, ty = threadIdx.y;   // 32 x 8
  const int k0 = blockIdx.y * 32, n0 = blockIdx.x * 32;
#pragma unroll
  for (int j = 0; j < 32; j += 8)
    tile[ty + j][tx] = W[(size_t)(k0 + ty + j) * 768 + n0 + tx];
  __syncthreads();
#pragma unroll
  for (int j = 0; j < 32; j += 8) {
    int n = ty + j;
    T[(size_t)(n0 + n) * 768 + k0 + tx] = (bf16)tile[tx][n];
  }
}

// ---------------- QKV GEMM: C[128x128] = A_bf16[m][k] * Wt[n][k]^T + bias ----------
// Single-buffer 32KB DMA staging, 2 barriers/iter; 576 blocks XCD-swizzled.
__global__ __launch_bounds__(256, 4) void gemm_qkv_kernel(
    const bf16* __restrict__ A0, const bf16* __restrict__ A1, const bf16* __restrict__ A2,
    const bf16* __restrict__ W0, const bf16* __restrict__ W1, const bf16* __restrict__ W2,
    const float* __restrict__ b0, const float* __restrict__ b1, const float* __restrict__ b2,
    bf16* __restrict__ Q, bf16* __restrict__ K, bf16* __restrict__ V) {
  __shared__ __align__(16) char smem[32768];
  const int bidx = blockIdx.x;
  const int xcd = bidx & 7, ii = bidx >> 3;   // ii 0..71
  const int nt = ii % 6, mzi = ii / 6;        // mzi 0..11
  const int mz = mzi * 8 + xcd;               // 0..95
  const int m = mz & 31, z = mz >> 5;
  const int m0 = m * 128, n0 = nt * 128;

  const bf16* A    = (z == 0) ? A0 : (z == 1) ? A1 : A2;
  const bf16* Wt   = (z == 0) ? W0 : (z == 1) ? W1 : W2;
  const float* bias = (z == 0) ? b0 : (z == 1) ? b1 : b2;
  bf16* outb = (z == 0) ? Q : (z == 1) ? K : V;
  const int mode = (z == 2) ? 1 : 0;

  const int t = threadIdx.x;
  const int w = t >> 6, lane = t & 63;
  const int wm = w >> 1, wn = w & 1;
  const int quad = lane >> 4, l15 = lane & 15;
  const int srow = lane >> 3, k8p = lane & 7;

  size_t offA[4], offB[4];
  int ldsOff[4];
#pragma unroll
  for (int i = 0; i < 4; ++i) {
    const int rl = w * 32 + i * 8 + srow;
    const int kk = k8p ^ (rl & 7);
    offA[i] = (size_t)(m0 + rl) * 768 + kk * 8;
    offB[i] = (size_t)(n0 + rl) * 768 + kk * 8;
    ldsOff[i] = (w * 32 + i * 8) * 128;   // bytes
  }

  f32x4 acc[4][4] = {};

  for (int kidx = 0; kidx < 12; ++kidx) {
    const int k1 = kidx * 64;
#pragma unroll
    for (int i = 0; i < 4; ++i) {
      async_load16(A  + offA[i] + k1, smem + ldsOff[i]);
      async_load16(Wt + offB[i] + k1, smem + 16384 + ldsOff[i]);
    }
    __syncthreads();   // DMA drained
    const bf16* As = (const bf16*)smem;
    const bf16* Bs = (const bf16*)(smem + 16384);
#pragma unroll
    for (int ks = 0; ks < 2; ++ks) {
      bf16x8 af[4], bfv[4];
      const int slot = (((ks * 4 + quad) ^ (lane & 7)) * 8);
#pragma unroll
      for (int mi = 0; mi < 4; ++mi)
        af[mi] = *(const bf16x8*)(As + (wm * 64 + mi * 16 + l15) * 64 + slot);
#pragma unroll
      for (int ni = 0; ni < 4; ++ni)
        bfv[ni] = *(const bf16x8*)(Bs + (wn * 64 + ni * 16 + l15) * 64 + slot);
#pragma unroll
      for (int mi = 0; mi < 4; ++mi)
#pragma unroll
        for (int ni = 0; ni < 4; ++ni)
          acc[mi][ni] = __builtin_amdgcn_mfma_f32_16x16x32_bf16(af[mi], bfv[ni], acc[mi][ni], 0, 0, 0);
    }
    __syncthreads();   // reads done before next DMA overwrites
  }

#pragma unroll
  for (int ni = 0; ni < 4; ++ni) {
    const float bc = bias[n0 + wn * 64 + ni * 16 + l15];
#pragma unroll
    for (int mi = 0; mi < 4; ++mi)
#pragma unroll
      for (int r = 0; r < 4; ++r) acc[mi][ni][r] += bc;
  }

  // epilogue in two 64-row halves
  if (mode == 0) {
    bf16* Ce = (bf16*)smem;
#pragma unroll
    for (int hh = 0; hh < 2; ++hh) {
      if (wm == hh) {
#pragma unroll
        for (int ni = 0; ni < 4; ++ni) {
          const int col = wn * 64 + ni * 16 + l15;
#pragma unroll
          for (int mi = 0; mi < 4; ++mi) {
            const int row = mi * 16 + quad * 4;   // local 0..63
#pragma unroll
            for (int r = 0; r < 4; ++r)
              Ce[(row + r) * 136 + col] = (bf16)acc[mi][ni][r];
          }
        }
      }
      __syncthreads();
#pragma unroll
      for (int j = 0; j < 4; ++j) {
        const int ci = j * 256 + t;                 // 0..1023
        const int row = ci >> 4, c8 = (ci & 15) * 8;
        bf16x8 vv = *(const bf16x8*)(Ce + row * 136 + c8);
        const int rg = m0 + hh * 64 + row, cg = n0 + c8;
        const int bb = rg >> 11, s = rg & 2047;
        const int h = cg >> 6, d = cg & 63;
        *(bf16x8*)(outb + ((size_t)(bb * 12 + h) * 2048 + s) * 64 + d) = vv;
      }
      __syncthreads();
    }
  } else {
    bf16* Ct = (bf16*)smem;   // [col 128][row 64+pad], stride 72
#pragma unroll
    for (int hh = 0; hh < 2; ++hh) {
      if (wm == hh) {
#pragma unroll
        for (int ni = 0; ni < 4; ++ni) {
          const int col = wn * 64 + ni * 16 + l15;
#pragma unroll
          for (int mi = 0; mi < 4; ++mi) {
            const int row = mi * 16 + quad * 4;   // local 0..63
            bf16x4 pv;
            pv[0] = (bf16)acc[mi][ni][0]; pv[1] = (bf16)acc[mi][ni][1];
            pv[2] = (bf16)acc[mi][ni][2]; pv[3] = (bf16)acc[mi][ni][3];
            *(bf16x4*)(Ct + (size_t)col * 72 + row) = pv;
          }
        }
      }
      __syncthreads();
#pragma unroll
      for (int j = 0; j < 4; ++j) {
        const int ci = j * 256 + t;                 // 0..1023
        const int col = ci >> 3, r8 = (ci & 7) * 8;
        bf16x8 vv = *(const bf16x8*)(Ct + col * 72 + r8);
        const int cg = n0 + col;
        const int h = cg >> 6, d = cg & 63;
        const int rg = m0 + hh * 64 + r8;
        const int bb = rg >> 11, s = rg & 2047;
        *(bf16x8*)(outb + ((size_t)(bb * 12 + h) * 64 + d) * 2048 + s) = vv;
      }
      __syncthreads();
    }
  }
}

// ---------------- flash attention, 4-way split-K, single-buffer 32KB DMA ----------------
__global__ __launch_bounds__(256, 4) void attn_kernel(
    const bf16* __restrict__ Qh, const bf16* __restrict__ Kh,
    const bf16* __restrict__ Vt,
    bf16* __restrict__ O0, bf16* __restrict__ O1,
    bf16* __restrict__ O2, bf16* __restrict__ O3,
    float* __restrict__ L0, float* __restrict__ L1,
    float* __restrict__ L2, float* __restrict__ L3) {
  const int ent = chunk_tab[blockIdx.x / 24];
  const int bh = blockIdx.x % 24;
  const int qt = ent & 15, c = ent >> 4;
  const int q0 = qt * 128;
  const int kt_begin = c * 8;
  const int ntiles = 2 * qt + 2;
  const int kt_end = (kt_begin + 8 < ntiles) ? kt_begin + 8 : ntiles;

  __shared__ __align__(16) char smem[32768];
  bf16* Ps = (bf16*)(smem + 16384);   // [128 q][64 key] swizzled (wave-private rows)

  const int t = threadIdx.x;
  const int w = t >> 6, lane = t & 63, quad = lane >> 4, l15 = lane & 15;
  const int srow = lane >> 3, k8p = lane & 7;
  const bf16* Qp = Qh + (size_t)bh * (2048 * 64);
  const bf16* Kp = Kh + (size_t)bh * (2048 * 64);
  const bf16* Vp = Vt + (size_t)bh * (64 * 2048);

  size_t offK[2], offV[2];
  int ldsOff[2];
#pragma unroll
  for (int i = 0; i < 2; ++i) {
    const int rl = w * 16 + i * 8 + srow;
    const int kk = k8p ^ (rl & 7);
    offK[i] = (size_t)rl * 64 + kk * 8;
    offV[i] = (size_t)rl * 2048 + kk * 8;
    ldsOff[i] = (w * 16 + i * 8) * 128;   // bytes
  }

  bf16x8 qf[2][2];
#pragma unroll
  for (int mi = 0; mi < 2; ++mi)
#pragma unroll
    for (int ks = 0; ks < 2; ++ks) {
      const int qrow = q0 + w * 32 + mi * 16 + l15;
      qf[mi][ks] = *(const bf16x8*)(Qp + (size_t)qrow * 64 + ks * 32 + quad * 8);
    }

  f32x4 o[2][4] = {};
  float lp[2] = {0.f, 0.f};
  const float sc = 0.125f * 1.44269504f;

  for (int kt = kt_begin; kt < kt_end; ++kt) {
    const int k0 = kt * 64;
#pragma unroll
    for (int i = 0; i < 2; ++i) {
      async_load16(Kp + offK[i] + (size_t)k0 * 64, smem + ldsOff[i]);
      async_load16(Vp + offV[i] + k0,              smem + 8192 + ldsOff[i]);
    }
    __syncthreads();
    const bf16* Ks = (const bf16*)smem;
    const bf16* Vs = (const bf16*)(smem + 8192);

    // S^T = K Q^T : col = q (l15), row = key (ni*16+quad*4+r)
    f32x4 st[4][2] = {};
#pragma unroll
    for (int ks = 0; ks < 2; ++ks) {
      const int slot = (((ks * 4 + quad) ^ (lane & 7)) * 8);
      bf16x8 kf[4];
#pragma unroll
      for (int ni = 0; ni < 4; ++ni)
        kf[ni] = *(const bf16x8*)(Ks + (ni * 16 + l15) * 64 + slot);
#pragma unroll
      for (int ni = 0; ni < 4; ++ni)
#pragma unroll
        for (int mi = 0; mi < 2; ++mi)
          st[ni][mi] = __builtin_amdgcn_mfma_f32_16x16x32_bf16(kf[ni], qf[mi][ks], st[ni][mi], 0, 0, 0);
    }

    const bool diag = (k0 + 63 > q0);
#pragma unroll
    for (int mi = 0; mi < 2; ++mi) {
      const int q_local = w * 32 + mi * 16 + l15;
      const int qg = q0 + q_local;
#pragma unroll
      for (int ni = 0; ni < 4; ++ni) {
        bf16x4 pv;
#pragma unroll
        for (int r = 0; r < 4; ++r) {
          float p = __builtin_amdgcn_exp2f(st[ni][mi][r] * sc);
          if (diag && (k0 + ni * 16 + quad * 4 + r > qg)) p = 0.0f;
          lp[mi] += p;
          pv[r] = (bf16)p;
        }
        const int cc = ni * 2 + (quad >> 1);
        *(bf16x4*)(Ps + q_local * 64 + ((cc ^ (q_local & 7)) << 3) + ((quad & 1) << 2)) = pv;
      }
    }

#pragma unroll
    for (int ks = 0; ks < 2; ++ks) {
      const int slot = (((ks * 4 + quad) ^ (lane & 7)) * 8);
      bf16x8 pf[2], vfr[4];
#pragma unroll
      for (int mi = 0; mi < 2; ++mi)
        pf[mi] = *(const bf16x8*)(Ps + (w * 32 + mi * 16 + l15) * 64 + slot);
#pragma unroll
      for (int di = 0; di < 4; ++di)
        vfr[di] = *(const bf16x8*)(Vs + (di * 16 + l15) * 64 + slot);
#pragma unroll
      for (int mi = 0; mi < 2; ++mi)
#pragma unroll
        for (int di = 0; di < 4; ++di)
          o[mi][di] = __builtin_amdgcn_mfma_f32_16x16x32_bf16(pf[mi], vfr[di], o[mi][di], 0, 0, 0);
    }
    __syncthreads();
  }

  bf16* Op; float* Lp_;
  switch (c) {
    case 0: Op = O0; Lp_ = L0; break;
    case 1: Op = O1; Lp_ = L1; break;
    case 2: Op = O2; Lp_ = L2; break;
    default: Op = O3; Lp_ = L3; break;
  }
  const int rows_c = 2048 - 512 * c;
  const size_t rbase = (size_t)bh * rows_c + (q0 - 512 * c);

  // L reduction + store (tiny)
#pragma unroll
  for (int mi = 0; mi < 2; ++mi) {
    float l = lp[mi];
    l += __shfl_xor(l, 16);
    l += __shfl_xor(l, 32);
    if (quad == 0) Lp_[rbase + w * 32 + mi * 16 + l15] = l;
  }

  // Coalesced O epilogue: C-layout regs -> LDS [128 rows][stride 68] -> bf16x8 stores.
  // Write banks: quads land 8 banks apart (4*68*2/4 = 136/4=34 -> 4 rows = 8 banks),
  // l15 pairs 2-way (free, m136).
  bf16* Ot = (bf16*)smem;   // 128*68*2 = 17408 B, loop barrier above makes it free
#pragma unroll
  for (int mi = 0; mi < 2; ++mi)
#pragma unroll
    for (int di = 0; di < 4; ++di) {
      const int d = di * 16 + l15;
#pragma unroll
      for (int r = 0; r < 4; ++r)
        Ot[(w * 32 + mi * 16 + quad * 4 + r) * 68 + d] = (bf16)o[mi][di][r];
    }
  __syncthreads();
#pragma unroll
  for (int j = 0; j < 4; ++j) {
    const int ci = j * 256 + t;            // 0..1023
    const int row = ci >> 3, c8 = (ci & 7) * 8;
    bf16x8 vv = *(const bf16x8*)(Ot + row * 68 + c8);
    *(bf16x8*)(Op + (rbase + row) * 64 + c8) = vv;
  }
}

// ---------------- lsum: Linv[bh*2048+s] = 1 / sum_c Lc ----------------
__global__ __launch_bounds__(256) void lsum_kernel(
    const float* __restrict__ L0, const float* __restrict__ L1,
    const float* __restrict__ L2, const float* __restrict__ L3,
    float* __restrict__ Linv) {
  const int row = blockIdx.x * 256 + threadIdx.x;  // 49152
  const int bh = row >> 11, s = row & 2047;
  float l = L0[row];
  if (s >= 512)  l += L1[(size_t)bh * 1536 + (s - 512)];
  if (s >= 1024) l += L2[(size_t)bh * 1024 + (s - 1024)];
  if (s >= 1536) l += L3[(size_t)bh * 512  + (s - 1536)];
  Linv[row] = 1.0f / l;
}

// ---------------- out GEMM (fused combine+normalize): out = attn * Wo^T + bo ------
// 64-row m-tiles -> 384 blocks, 24KB LDS single-buffer; A (partial sums) staged via
// register prefetch (barrier-immune), B via DMA. XCD-swizzled.
__global__ __launch_bounds__(256, 4) void gemm_out_kernel(
    const bf16* __restrict__ O0, const bf16* __restrict__ O1,
    const bf16* __restrict__ O2, const bf16* __restrict__ O3,
    const float* __restrict__ Linv, const bf16* __restrict__ Wt,
    const float* __restrict__ bias, float* __restrict__ out) {
  __shared__ __align__(16) char smem[24576];   // As 8KB @0, Bs 16KB @8192
  const int bidx = blockIdx.x;                 // 384
  const int xcd = bidx & 7, ii = bidx >> 3;    // ii 0..47
  const int nt = ii % 6, mg = ii / 6;          // mg 0..7
  const int mt = mg * 8 + xcd;                 // 0..63
  const int m0 = mt * 64, n0 = nt * 128;
  const int bb = mt >> 5;                      // batch
  const int s0 = (mt & 31) * 64;               // 0..1984
  const int nch = 1 + (s0 >= 512) + (s0 >= 1024) + (s0 >= 1536);

  const int t = threadIdx.x;
  const int w = t >> 6, lane = t & 63;
  const int wm = w >> 1, wn = w & 1;
  const int quad = lane >> 4, l15 = lane & 15;
  const int srow = lane >> 3, k8p = lane & 7;

  size_t offB[4]; int ldsOffB[4];
#pragma unroll
  for (int i = 0; i < 4; ++i) {
    const int rl = w * 32 + i * 8 + srow;
    const int kk = k8p ^ (rl & 7);
    offB[i] = (size_t)(n0 + rl) * 768 + kk * 8;
    ldsOffB[i] = (w * 32 + i * 8) * 128;   // bytes
  }
  // A staging: row arow (0..63), two 8-col chunks
  const int arow = t >> 2;
  const int ac2 = (t & 3) * 2;
  const int sA = s0 + arow;
  size_t ro0[2], ro1[2], ro2[2], ro3[2];
  int apos[2];
#pragma unroll
  for (int j = 0; j < 2; ++j) {
    const int cch = ac2 + j;
    ro0[j] = (size_t)sA * 64 + cch * 8;
    ro1[j] = (size_t)(sA - 512) * 64 + cch * 8;
    ro2[j] = (size_t)(sA - 1024) * 64 + cch * 8;
    ro3[j] = (size_t)(sA - 1536) * 64 + cch * 8;
    apos[j] = arow * 64 + ((cch ^ (arow & 7)) << 3);
  }

  f32x4 acc[2][4] = {};
  bf16x8 pa0[2], pa1[2], pa2[2], pa3[2];
  float lv;

  auto loadA = [&](int kk) {
    const size_t bh = (size_t)(bb * 12 + kk);
    lv = Linv[bh * 2048 + sA];
#pragma unroll
    for (int j = 0; j < 2; ++j) pa0[j] = *(const bf16x8*)(O0 + bh * 131072 + ro0[j]);
    if (nch >= 2)
#pragma unroll
      for (int j = 0; j < 2; ++j) pa1[j] = *(const bf16x8*)(O1 + bh * 98304 + ro1[j]);
    if (nch >= 3)
#pragma unroll
      for (int j = 0; j < 2; ++j) pa2[j] = *(const bf16x8*)(O2 + bh * 65536 + ro2[j]);
    if (nch >= 4)
#pragma unroll
      for (int j = 0; j < 2; ++j) pa3[j] = *(const bf16x8*)(O3 + bh * 32768 + ro3[j]);
  };
  auto writeA = [&]() {
    bf16* As = (bf16*)smem;
#pragma unroll
    for (int j = 0; j < 2; ++j) {
      float f[8];
#pragma unroll
      for (int k = 0; k < 8; ++k) f[k] = (float)pa0[j][k];
      if (nch >= 2)
#pragma unroll
        for (int k = 0; k < 8; ++k) f[k] += (float)pa1[j][k];
      if (nch >= 3)
#pragma unroll
        for (int k = 0; k < 8; ++k) f[k] += (float)pa2[j][k];
      if (nch >= 4)
#pragma unroll
        for (int k = 0; k < 8; ++k) f[k] += (float)pa3[j][k];
      bf16x8 o;
#pragma unroll
      for (int k = 0; k < 8; ++k) o[k] = (bf16)(f[k] * lv);
      *(bf16x8*)(As + apos[j]) = o;
    }
  };

  loadA(0);
  for (int kidx = 0; kidx < 12; ++kidx) {
    writeA();
    const int k1 = kidx * 64;
#pragma unroll
    for (int i = 0; i < 4; ++i)
      async_load16(Wt + offB[i] + k1, smem + 8192 + ldsOffB[i]);
    __syncthreads();   // drains ds_write + DMA
    if (kidx < 11) loadA(kidx + 1);   // register prefetch, barrier-immune
    const bf16* As = (const bf16*)smem;
    const bf16* Bs = (const bf16*)(smem + 8192);
#pragma unroll
    for (int ks = 0; ks < 2; ++ks) {
      bf16x8 af[2], bfv[4];
      const int slot = (((ks * 4 + quad) ^ (lane & 7)) * 8);
#pragma unroll
      for (int mi = 0; mi < 2; ++mi)
        af[mi] = *(const bf16x8*)(As + (wm * 32 + mi * 16 + l15) * 64 + slot);
#pragma unroll
      for (int ni = 0; ni < 4; ++ni)
        bfv[ni] = *(const bf16x8*)(Bs + (wn * 64 + ni * 16 + l15) * 64 + slot);
#pragma unroll
      for (int mi = 0; mi < 2; ++mi)
#pragma unroll
        for (int ni = 0; ni < 4; ++ni)
          acc[mi][ni] = __builtin_amdgcn_mfma_f32_16x16x32_bf16(af[mi], bfv[ni], acc[mi][ni], 0, 0, 0);
    }
    __syncthreads();   // reads done before next writeA/DMA
  }

#pragma unroll
  for (int ni = 0; ni < 4; ++ni) {
    const float bc = bias[n0 + wn * 64 + ni * 16 + l15];
#pragma unroll
    for (int mi = 0; mi < 2; ++mi)
#pragma unroll
      for (int r = 0; r < 4; ++r) acc[mi][ni][r] += bc;
  }

#pragma unroll
  for (int ni = 0; ni < 4; ++ni) {
    const int col = n0 + wn * 64 + ni * 16 + l15;
#pragma unroll
    for (int mi = 0; mi < 2; ++mi) {
      const int row = m0 + wm * 32 + mi * 16 + quad * 4;
#pragma unroll
      for (int r = 0; r < 4; ++r)
        out[(size_t)(row + r) * 768 + col] = acc[mi][ni][r];
    }
  }
}

extern "C" void kernel_launch(void* const* d_in, const int* in_sizes, int n_in,
                              void* d_out, int out_size, void* d_ws, size_t ws_size,
                              hipStream_t stream) {
  const float* query = (const float*)d_in[0];
  const float* key   = (const float*)d_in[1];
  const float* value = (const float*)d_in[2];
  // d_in[3] = mask (causal triu, implemented analytically)
  const float* Wq = (const float*)d_in[4];
  const float* bq = (const float*)d_in[5];
  const float* Wk = (const float*)d_in[6];
  const float* bk = (const float*)d_in[7];
  const float* Wv = (const float*)d_in[8];
  const float* bv = (const float*)d_in[9];
  const float* Wo = (const float*)d_in[10];
  const float* bo = (const float*)d_in[11];
  float* out = (float*)d_out;

  char* ws = (char*)d_ws;
  // region 1 [0, 18874368): qb/kb/vb during projections; O/L/Linv after (overlay)
  bf16* qb   = (bf16*)(ws);
  bf16* kb   = (bf16*)(ws + 6291456);
  bf16* vb   = (bf16*)(ws + 12582912);
  bf16* O0   = (bf16*)(ws);              // 24*2048*64 bf16 = 6291456
  bf16* O1   = (bf16*)(ws + 6291456);    // 24*1536*64 = 4718592
  bf16* O2   = (bf16*)(ws + 11010048);   // 24*1024*64 = 3145728
  bf16* O3   = (bf16*)(ws + 14155776);   // 24*512*64  = 1572864
  float* L0  = (float*)(ws + 15728640);  // 24*2048 f32
  float* L1  = (float*)(ws + 15925248);
  float* L2  = (float*)(ws + 16072704);
  float* L3  = (float*)(ws + 16171008);
  float* Liv = (float*)(ws + 16220160);  // ends 16416768 < 18874368
  // region 2: weights + head tensors
  bf16* wtq  = (bf16*)(ws + 18874368);
  bf16* wtk  = (bf16*)(ws + 20054016);
  bf16* wtv  = (bf16*)(ws + 21233664);
  bf16* wto  = (bf16*)(ws + 22413312);
  bf16* Qh   = (bf16*)(ws + 23592960);
  bf16* Kh   = (bf16*)(ws + 29884416);
  bf16* Vtb  = (bf16*)(ws + 36175872);   // ends 42467328 (~40.5 MB)

  convert_kernel<<<dim3(1536, 3), 256, 0, stream>>>(query, key, value, qb, kb, vb);
  transpose_w_kernel<<<dim3(24, 24, 4), dim3(32, 8), 0, stream>>>(Wq, Wk, Wv, Wo, wtq, wtk, wtv, wto);
  gemm_qkv_kernel<<<dim3(576), 256, 0, stream>>>(qb, kb, vb, wtq, wtk, wtv, bq, bk, bv, Qh, Kh, Vtb);
  attn_kernel<<<dim3(960), 256, 0, stream>>>(Qh, Kh, Vtb, O0, O1, O2, O3, L0, L1, L2, L3);
  lsum_kernel<<<dim3(192), 256, 0, stream>>>(L0, L1, L2, L3, Liv);
  gemm_out_kernel<<<dim3(384), 256, 0, stream>>>(O0, O1, O2, O3, Liv, wto, bo, out);
}

// Round 11
// 187.501 us; speedup vs baseline: 1.2020x; 1.0292x over previous
//
#include <hip/hip_runtime.h>

// MultiHeadAttention: B=2,S=2048,D=768,H=12,depth=64. fp32 in/out, bf16 MFMA inside.
// R11 = R7 baseline (189us) with: attn epilogue reverted to R7 scalar stores,
// lsum fused into gemm_out (LDS LivS), convert+transpose merged into one prep
// dispatch. 4 dispatches: prep -> QKV gemm -> flash attn (4-way split-K) -> out gemm.

typedef __bf16 bf16;
typedef __bf16 bf16x8 __attribute__((ext_vector_type(8)));
typedef __bf16 bf16x4 __attribute__((ext_vector_type(4)));
typedef float  f32x4  __attribute__((ext_vector_type(4)));

__device__ __forceinline__ void async_load16(const void* g, void* l) {
  __builtin_amdgcn_global_load_lds(
      (__attribute__((address_space(1))) void*)g,
      (__attribute__((address_space(3))) void*)l, 16, 0, 0);
}

// chunk table: (qt | c<<4), descending tile count (long blocks dispatch first)
__constant__ unsigned char chunk_tab[40] = {
  3, 4, 5, 6, 7, 8, 9, 10, 11, 12, 13, 14, 15,
  7 | 16, 8 | 16, 9 | 16, 10 | 16, 11 | 16, 12 | 16, 13 | 16, 14 | 16, 15 | 16,
  11 | 32, 12 | 32, 13 | 32, 14 | 32, 15 | 32,
  15 | 48,
  2, 6 | 16, 10 | 32, 14 | 48,
  1, 5 | 16, 9 | 32, 13 | 48,
  0, 4 | 16, 8 | 32, 12 | 48,
};

// ---------------- prep: fp32->bf16 convert (q,k,v) + W transpose, one dispatch ----
// blocks [0,4608): convert; blocks [4608,6912): Wt transpose.
__global__ __launch_bounds__(256) void prep_kernel(
    const float* __restrict__ q, const float* __restrict__ k,
    const float* __restrict__ v, bf16* __restrict__ qo,
    bf16* __restrict__ ko, bf16* __restrict__ vo,
    const float* __restrict__ W0, const float* __restrict__ W1,
    const float* __restrict__ W2, const float* __restrict__ W3,
    bf16* __restrict__ T0, bf16* __restrict__ T1,
    bf16* __restrict__ T2, bf16* __restrict__ T3) {
  __shared__ float tile[32][33];
  const int b = blockIdx.x;
  const int t = threadIdx.x;
  if (b < 4608) {
    const int which = b / 1536, bx = b % 1536;
    const float* src; bf16* dst;
    if (which == 0)      { src = q; dst = qo; }
    else if (which == 1) { src = k; dst = ko; }
    else                 { src = v; dst = vo; }
    size_t i = ((size_t)bx * 256 + t) * 8;
    f32x4 a = *(const f32x4*)(src + i);
    f32x4 bb = *(const f32x4*)(src + i + 4);
    bf16x8 o;
    o[0]=(bf16)a[0]; o[1]=(bf16)a[1]; o[2]=(bf16)a[2]; o[3]=(bf16)a[3];
    o[4]=(bf16)bb[0]; o[5]=(bf16)bb[1]; o[6]=(bf16)bb[2]; o[7]=(bf16)bb[3];
    *(bf16x8*)(dst + i) = o;
    return;
  }
  const int idx = b - 4608;              // 0..2303
  const int z = idx / 576, rest = idx % 576;
  const int by = rest / 24, bx = rest % 24;
  const float* W; bf16* T;
  switch (z) {
    case 0: W = W0; T = T0; break;
    case 1: W = W1; T = T1; break;
    case 2: W = W2; T = T2; break;
    default: W = W3; T = T3; break;
  }
  const int tx = t & 31, ty = t >> 5;    // 32 x 8
  const int k0 = by * 32, n0 = bx * 32;
#pragma unroll
  for (int j = 0; j < 32; j += 8)
    tile[ty + j][tx] = W[(size_t)(k0 + ty + j) * 768 + n0 + tx];
  __syncthreads();
#pragma unroll
  for (int j = 0; j < 32; j += 8) {
    int n = ty + j;
    T[(size_t)(n0 + n) * 768 + k0 + tx] = (bf16)tile[tx][n];
  }
}

// ---------------- QKV GEMM: C[128x128] = A_bf16[m][k] * Wt[n][k]^T + bias ----------
// Single-buffer 32KB DMA staging, 2 barriers/iter; 576 blocks XCD-swizzled. (R7)
__global__ __launch_bounds__(256, 4) void gemm_qkv_kernel(
    const bf16* __restrict__ A0, const bf16* __restrict__ A1, const bf16* __restrict__ A2,
    const bf16* __restrict__ W0, const bf16* __restrict__ W1, const bf16* __restrict__ W2,
    const float* __restrict__ b0, const float* __restrict__ b1, const float* __restrict__ b2,
    bf16* __restrict__ Q, bf16* __restrict__ K, bf16* __restrict__ V) {
  __shared__ __align__(16) char smem[32768];
  const int bidx = blockIdx.x;
  const int xcd = bidx & 7, ii = bidx >> 3;   // ii 0..71
  const int nt = ii % 6, mzi = ii / 6;        // mzi 0..11
  const int mz = mzi * 8 + xcd;               // 0..95
  const int m = mz & 31, z = mz >> 5;
  const int m0 = m * 128, n0 = nt * 128;

  const bf16* A    = (z == 0) ? A0 : (z == 1) ? A1 : A2;
  const bf16* Wt   = (z == 0) ? W0 : (z == 1) ? W1 : W2;
  const float* bias = (z == 0) ? b0 : (z == 1) ? b1 : b2;
  bf16* outb = (z == 0) ? Q : (z == 1) ? K : V;
  const int mode = (z == 2) ? 1 : 0;

  const int t = threadIdx.x;
  const int w = t >> 6, lane = t & 63;
  const int wm = w >> 1, wn = w & 1;
  const int quad = lane >> 4, l15 = lane & 15;
  const int srow = lane >> 3, k8p = lane & 7;

  size_t offA[4], offB[4];
  int ldsOff[4];
#pragma unroll
  for (int i = 0; i < 4; ++i) {
    const int rl = w * 32 + i * 8 + srow;
    const int kk = k8p ^ (rl & 7);
    offA[i] = (size_t)(m0 + rl) * 768 + kk * 8;
    offB[i] = (size_t)(n0 + rl) * 768 + kk * 8;
    ldsOff[i] = (w * 32 + i * 8) * 128;   // bytes
  }

  f32x4 acc[4][4] = {};

  for (int kidx = 0; kidx < 12; ++kidx) {
    const int k1 = kidx * 64;
#pragma unroll
    for (int i = 0; i < 4; ++i) {
      async_load16(A  + offA[i] + k1, smem + ldsOff[i]);
      async_load16(Wt + offB[i] + k1, smem + 16384 + ldsOff[i]);
    }
    __syncthreads();   // DMA drained
    const bf16* As = (const bf16*)smem;
    const bf16* Bs = (const bf16*)(smem + 16384);
#pragma unroll
    for (int ks = 0; ks < 2; ++ks) {
      bf16x8 af[4], bfv[4];
      const int slot = (((ks * 4 + quad) ^ (lane & 7)) * 8);
#pragma unroll
      for (int mi = 0; mi < 4; ++mi)
        af[mi] = *(const bf16x8*)(As + (wm * 64 + mi * 16 + l15) * 64 + slot);
#pragma unroll
      for (int ni = 0; ni < 4; ++ni)
        bfv[ni] = *(const bf16x8*)(Bs + (wn * 64 + ni * 16 + l15) * 64 + slot);
#pragma unroll
      for (int mi = 0; mi < 4; ++mi)
#pragma unroll
        for (int ni = 0; ni < 4; ++ni)
          acc[mi][ni] = __builtin_amdgcn_mfma_f32_16x16x32_bf16(af[mi], bfv[ni], acc[mi][ni], 0, 0, 0);
    }
    __syncthreads();   // reads done before next DMA overwrites
  }

#pragma unroll
  for (int ni = 0; ni < 4; ++ni) {
    const float bc = bias[n0 + wn * 64 + ni * 16 + l15];
#pragma unroll
    for (int mi = 0; mi < 4; ++mi)
#pragma unroll
      for (int r = 0; r < 4; ++r) acc[mi][ni][r] += bc;
  }

  // epilogue in two 64-row halves
  if (mode == 0) {
    bf16* Ce = (bf16*)smem;
#pragma unroll
    for (int hh = 0; hh < 2; ++hh) {
      if (wm == hh) {
#pragma unroll
        for (int ni = 0; ni < 4; ++ni) {
          const int col = wn * 64 + ni * 16 + l15;
#pragma unroll
          for (int mi = 0; mi < 4; ++mi) {
            const int row = mi * 16 + quad * 4;   // local 0..63
#pragma unroll
            for (int r = 0; r < 4; ++r)
              Ce[(row + r) * 136 + col] = (bf16)acc[mi][ni][r];
          }
        }
      }
      __syncthreads();
#pragma unroll
      for (int j = 0; j < 4; ++j) {
        const int ci = j * 256 + t;                 // 0..1023
        const int row = ci >> 4, c8 = (ci & 15) * 8;
        bf16x8 vv = *(const bf16x8*)(Ce + row * 136 + c8);
        const int rg = m0 + hh * 64 + row, cg = n0 + c8;
        const int bb = rg >> 11, s = rg & 2047;
        const int h = cg >> 6, d = cg & 63;
        *(bf16x8*)(outb + ((size_t)(bb * 12 + h) * 2048 + s) * 64 + d) = vv;
      }
      __syncthreads();
    }
  } else {
    bf16* Ct = (bf16*)smem;   // [col 128][row 64+pad], stride 72
#pragma unroll
    for (int hh = 0; hh < 2; ++hh) {
      if (wm == hh) {
#pragma unroll
        for (int ni = 0; ni < 4; ++ni) {
          const int col = wn * 64 + ni * 16 + l15;
#pragma unroll
          for (int mi = 0; mi < 4; ++mi) {
            const int row = mi * 16 + quad * 4;   // local 0..63
            bf16x4 pv;
            pv[0] = (bf16)acc[mi][ni][0]; pv[1] = (bf16)acc[mi][ni][1];
            pv[2] = (bf16)acc[mi][ni][2]; pv[3] = (bf16)acc[mi][ni][3];
            *(bf16x4*)(Ct + (size_t)col * 72 + row) = pv;
          }
        }
      }
      __syncthreads();
#pragma unroll
      for (int j = 0; j < 4; ++j) {
        const int ci = j * 256 + t;                 // 0..1023
        const int col = ci >> 3, r8 = (ci & 7) * 8;
        bf16x8 vv = *(const bf16x8*)(Ct + col * 72 + r8);
        const int cg = n0 + col;
        const int h = cg >> 6, d = cg & 63;
        const int rg = m0 + hh * 64 + r8;
        const int bb = rg >> 11, s = rg & 2047;
        *(bf16x8*)(outb + ((size_t)(bb * 12 + h) * 64 + d) * 2048 + s) = vv;
      }
      __syncthreads();
    }
  }
}

// ---------------- flash attention, 4-way split-K, single-buffer 32KB DMA (R7) -------
__global__ __launch_bounds__(256, 4) void attn_kernel(
    const bf16* __restrict__ Qh, const bf16* __restrict__ Kh,
    const bf16* __restrict__ Vt,
    bf16* __restrict__ O0, bf16* __restrict__ O1,
    bf16* __restrict__ O2, bf16* __restrict__ O3,
    float* __restrict__ L0, float* __restrict__ L1,
    float* __restrict__ L2, float* __restrict__ L3) {
  const int ent = chunk_tab[blockIdx.x / 24];
  const int bh = blockIdx.x % 24;
  const int qt = ent & 15, c = ent >> 4;
  const int q0 = qt * 128;
  const int kt_begin = c * 8;
  const int ntiles = 2 * qt + 2;
  const int kt_end = (kt_begin + 8 < ntiles) ? kt_begin + 8 : ntiles;

  __shared__ __align__(16) char smem[32768];
  bf16* Ps = (bf16*)(smem + 16384);   // [128 q][64 key] swizzled (wave-private rows)

  const int t = threadIdx.x;
  const int w = t >> 6, lane = t & 63, quad = lane >> 4, l15 = lane & 15;
  const int srow = lane >> 3, k8p = lane & 7;
  const bf16* Qp = Qh + (size_t)bh * (2048 * 64);
  const bf16* Kp = Kh + (size_t)bh * (2048 * 64);
  const bf16* Vp = Vt + (size_t)bh * (64 * 2048);

  size_t offK[2], offV[2];
  int ldsOff[2];
#pragma unroll
  for (int i = 0; i < 2; ++i) {
    const int rl = w * 16 + i * 8 + srow;
    const int kk = k8p ^ (rl & 7);
    offK[i] = (size_t)rl * 64 + kk * 8;
    offV[i] = (size_t)rl * 2048 + kk * 8;
    ldsOff[i] = (w * 16 + i * 8) * 128;   // bytes
  }

  bf16x8 qf[2][2];
#pragma unroll
  for (int mi = 0; mi < 2; ++mi)
#pragma unroll
    for (int ks = 0; ks < 2; ++ks) {
      const int qrow = q0 + w * 32 + mi * 16 + l15;
      qf[mi][ks] = *(const bf16x8*)(Qp + (size_t)qrow * 64 + ks * 32 + quad * 8);
    }

  f32x4 o[2][4] = {};
  float lp[2] = {0.f, 0.f};
  const float sc = 0.125f * 1.44269504f;

  for (int kt = kt_begin; kt < kt_end; ++kt) {
    const int k0 = kt * 64;
#pragma unroll
    for (int i = 0; i < 2; ++i) {
      async_load16(Kp + offK[i] + (size_t)k0 * 64, smem + ldsOff[i]);
      async_load16(Vp + offV[i] + k0,              smem + 8192 + ldsOff[i]);
    }
    __syncthreads();
    const bf16* Ks = (const bf16*)smem;
    const bf16* Vs = (const bf16*)(smem + 8192);

    // S^T = K Q^T : col = q (l15), row = key (ni*16+quad*4+r)
    f32x4 st[4][2] = {};
#pragma unroll
    for (int ks = 0; ks < 2; ++ks) {
      const int slot = (((ks * 4 + quad) ^ (lane & 7)) * 8);
      bf16x8 kf[4];
#pragma unroll
      for (int ni = 0; ni < 4; ++ni)
        kf[ni] = *(const bf16x8*)(Ks + (ni * 16 + l15) * 64 + slot);
#pragma unroll
      for (int ni = 0; ni < 4; ++ni)
#pragma unroll
        for (int mi = 0; mi < 2; ++mi)
          st[ni][mi] = __builtin_amdgcn_mfma_f32_16x16x32_bf16(kf[ni], qf[mi][ks], st[ni][mi], 0, 0, 0);
    }

    const bool diag = (k0 + 63 > q0);
#pragma unroll
    for (int mi = 0; mi < 2; ++mi) {
      const int q_local = w * 32 + mi * 16 + l15;
      const int qg = q0 + q_local;
#pragma unroll
      for (int ni = 0; ni < 4; ++ni) {
        bf16x4 pv;
#pragma unroll
        for (int r = 0; r < 4; ++r) {
          float p = __builtin_amdgcn_exp2f(st[ni][mi][r] * sc);
          if (diag && (k0 + ni * 16 + quad * 4 + r > qg)) p = 0.0f;
          lp[mi] += p;
          pv[r] = (bf16)p;
        }
        const int cc = ni * 2 + (quad >> 1);
        *(bf16x4*)(Ps + q_local * 64 + ((cc ^ (q_local & 7)) << 3) + ((quad & 1) << 2)) = pv;
      }
    }

#pragma unroll
    for (int ks = 0; ks < 2; ++ks) {
      const int slot = (((ks * 4 + quad) ^ (lane & 7)) * 8);
      bf16x8 pf[2], vfr[4];
#pragma unroll
      for (int mi = 0; mi < 2; ++mi)
        pf[mi] = *(const bf16x8*)(Ps + (w * 32 + mi * 16 + l15) * 64 + slot);
#pragma unroll
      for (int di = 0; di < 4; ++di)
        vfr[di] = *(const bf16x8*)(Vs + (di * 16 + l15) * 64 + slot);
#pragma unroll
      for (int mi = 0; mi < 2; ++mi)
#pragma unroll
        for (int di = 0; di < 4; ++di)
          o[mi][di] = __builtin_amdgcn_mfma_f32_16x16x32_bf16(pf[mi], vfr[di], o[mi][di], 0, 0, 0);
    }
    __syncthreads();
  }

  bf16* Op; float* Lp_;
  switch (c) {
    case 0: Op = O0; Lp_ = L0; break;
    case 1: Op = O1; Lp_ = L1; break;
    case 2: Op = O2; Lp_ = L2; break;
    default: Op = O3; Lp_ = L3; break;
  }
  const int rows_c = 2048 - 512 * c;
  const size_t rbase = (size_t)bh * rows_c + (q0 - 512 * c);

#pragma unroll
  for (int mi = 0; mi < 2; ++mi) {
    float l = lp[mi];
    l += __shfl_xor(l, 16);
    l += __shfl_xor(l, 32);
    if (quad == 0) Lp_[rbase + w * 32 + mi * 16 + l15] = l;
#pragma unroll
    for (int di = 0; di < 4; ++di) {
      const int d = di * 16 + l15;
#pragma unroll
      for (int r = 0; r < 4; ++r) {
        const size_t row = rbase + w * 32 + mi * 16 + quad * 4 + r;
        Op[row * 64 + d] = (bf16)o[mi][di][r];
      }
    }
  }
}

// ---------------- out GEMM (fused combine+normalize+lsum): out = attn * Wo^T + bo ---
// 64-row m-tiles -> 384 blocks XCD-swizzled; A (partial sums) via register prefetch,
// B via DMA; per-block Linv (768 vals) computed into LDS. 24KB+3KB LDS.
__global__ __launch_bounds__(256, 4) void gemm_out_kernel(
    const bf16* __restrict__ O0, const bf16* __restrict__ O1,
    const bf16* __restrict__ O2, const bf16* __restrict__ O3,
    const float* __restrict__ L0, const float* __restrict__ L1,
    const float* __restrict__ L2, const float* __restrict__ L3,
    const bf16* __restrict__ Wt, const float* __restrict__ bias,
    float* __restrict__ out) {
  __shared__ __align__(16) char smem[27648];   // As 8KB@0, Bs 16KB@8192, LivS 3KB@24576
  float* LivS = (float*)(smem + 24576);        // [12 heads][64 rows]
  const int bidx = blockIdx.x;                 // 384
  const int xcd = bidx & 7, ii = bidx >> 3;    // ii 0..47
  const int nt = ii % 6, mg = ii / 6;          // mg 0..7
  const int mt = mg * 8 + xcd;                 // 0..63
  const int m0 = mt * 64, n0 = nt * 128;
  const int bb = mt >> 5;                      // batch
  const int s0 = (mt & 31) * 64;               // 0..1984
  const int nch = 1 + (s0 >= 512) + (s0 >= 1024) + (s0 >= 1536);

  const int t = threadIdx.x;
  const int w = t >> 6, lane = t & 63;
  const int wm = w >> 1, wn = w & 1;
  const int quad = lane >> 4, l15 = lane & 15;
  const int srow = lane >> 3, k8p = lane & 7;

  // per-block Linv into LDS
  for (int idx = t; idx < 768; idx += 256) {
    const int kk = idx >> 6, r = idx & 63;
    const int s = s0 + r;
    const size_t bh = (size_t)(bb * 12 + kk);
    float l = L0[bh * 2048 + s];
    if (s >= 512)  l += L1[bh * 1536 + (s - 512)];
    if (s >= 1024) l += L2[bh * 1024 + (s - 1024)];
    if (s >= 1536) l += L3[bh * 512  + (s - 1536)];
    LivS[idx] = 1.0f / l;
  }

  size_t offB[4]; int ldsOffB[4];
#pragma unroll
  for (int i = 0; i < 4; ++i) {
    const int rl = w * 32 + i * 8 + srow;
    const int kk = k8p ^ (rl & 7);
    offB[i] = (size_t)(n0 + rl) * 768 + kk * 8;
    ldsOffB[i] = 8192 + (w * 32 + i * 8) * 128;   // bytes
  }
  // A staging: row arow (0..63), two 8-col chunks
  const int arow = t >> 2;
  const int ac2 = (t & 3) * 2;
  const int sA = s0 + arow;
  size_t ro0[2], ro1[2], ro2[2], ro3[2];
  int apos[2];
#pragma unroll
  for (int j = 0; j < 2; ++j) {
    const int cch = ac2 + j;
    ro0[j] = (size_t)sA * 64 + cch * 8;
    ro1[j] = (size_t)(sA - 512) * 64 + cch * 8;
    ro2[j] = (size_t)(sA - 1024) * 64 + cch * 8;
    ro3[j] = (size_t)(sA - 1536) * 64 + cch * 8;
    apos[j] = arow * 64 + ((cch ^ (arow & 7)) << 3);
  }

  f32x4 acc[2][4] = {};
  bf16x8 pa0[2], pa1[2], pa2[2], pa3[2];
  int kkcur = 0;

  auto loadA = [&](int kk) {
    kkcur = kk;
    const size_t bh = (size_t)(bb * 12 + kk);
#pragma unroll
    for (int j = 0; j < 2; ++j) pa0[j] = *(const bf16x8*)(O0 + bh * 131072 + ro0[j]);
    if (nch >= 2)
#pragma unroll
      for (int j = 0; j < 2; ++j) pa1[j] = *(const bf16x8*)(O1 + bh * 98304 + ro1[j]);
    if (nch >= 3)
#pragma unroll
      for (int j = 0; j < 2; ++j) pa2[j] = *(const bf16x8*)(O2 + bh * 65536 + ro2[j]);
    if (nch >= 4)
#pragma unroll
      for (int j = 0; j < 2; ++j) pa3[j] = *(const bf16x8*)(O3 + bh * 32768 + ro3[j]);
  };
  auto writeA = [&]() {
    bf16* As = (bf16*)smem;
    const float lv = LivS[kkcur * 64 + arow];
#pragma unroll
    for (int j = 0; j < 2; ++j) {
      float f[8];
#pragma unroll
      for (int k = 0; k < 8; ++k) f[k] = (float)pa0[j][k];
      if (nch >= 2)
#pragma unroll
        for (int k = 0; k < 8; ++k) f[k] += (float)pa1[j][k];
      if (nch >= 3)
#pragma unroll
        for (int k = 0; k < 8; ++k) f[k] += (float)pa2[j][k];
      if (nch >= 4)
#pragma unroll
        for (int k = 0; k < 8; ++k) f[k] += (float)pa3[j][k];
      bf16x8 o;
#pragma unroll
      for (int k = 0; k < 8; ++k) o[k] = (bf16)(f[k] * lv);
      *(bf16x8*)(As + apos[j]) = o;
    }
  };

  loadA(0);
  __syncthreads();   // LivS visible before writeA reads it
  for (int kidx = 0; kidx < 12; ++kidx) {
    writeA();
    const int k1 = kidx * 64;
#pragma unroll
    for (int i = 0; i < 4; ++i)
      async_load16(Wt + offB[i] - 8192/2*0 + k1, smem + ldsOffB[i]);
    __syncthreads();   // drains ds_write + DMA
    if (kidx < 11) loadA(kidx + 1);   // register prefetch, barrier-immune
    const bf16* As = (const bf16*)smem;
    const bf16* Bs = (const bf16*)(smem + 8192);
#pragma unroll
    for (int ks = 0; ks < 2; ++ks) {
      bf16x8 af[2], bfv[4];
      const int slot = (((ks * 4 + quad) ^ (lane & 7)) * 8);
#pragma unroll
      for (int mi = 0; mi < 2; ++mi)
        af[mi] = *(const bf16x8*)(As + (wm * 32 + mi * 16 + l15) * 64 + slot);
#pragma unroll
      for (int ni = 0; ni < 4; ++ni)
        bfv[ni] = *(const bf16x8*)(Bs + (wn * 64 + ni * 16 + l15) * 64 + slot);
#pragma unroll
      for (int mi = 0; mi < 2; ++mi)
#pragma unroll
        for (int ni = 0; ni < 4; ++ni)
          acc[mi][ni] = __builtin_amdgcn_mfma_f32_16x16x32_bf16(af[mi], bfv[ni], acc[mi][ni], 0, 0, 0);
    }
    __syncthreads();   // reads done before next writeA/DMA
  }

#pragma unroll
  for (int ni = 0; ni < 4; ++ni) {
    const float bc = bias[n0 + wn * 64 + ni * 16 + l15];
#pragma unroll
    for (int mi = 0; mi < 2; ++mi)
#pragma unroll
      for (int r = 0; r < 4; ++r) acc[mi][ni][r] += bc;
  }

#pragma unroll
  for (int ni = 0; ni < 4; ++ni) {
    const int col = n0 + wn * 64 + ni * 16 + l15;
#pragma unroll
    for (int mi = 0; mi < 2; ++mi) {
      const int row = m0 + wm * 32 + mi * 16 + quad * 4;
#pragma unroll
      for (int r = 0; r < 4; ++r)
        out[(size_t)(row + r) * 768 + col] = acc[mi][ni][r];
    }
  }
}

extern "C" void kernel_launch(void* const* d_in, const int* in_sizes, int n_in,
                              void* d_out, int out_size, void* d_ws, size_t ws_size,
                              hipStream_t stream) {
  const float* query = (const float*)d_in[0];
  const float* key   = (const float*)d_in[1];
  const float* value = (const float*)d_in[2];
  // d_in[3] = mask (causal triu, implemented analytically)
  const float* Wq = (const float*)d_in[4];
  const float* bq = (const float*)d_in[5];
  const float* Wk = (const float*)d_in[6];
  const float* bk = (const float*)d_in[7];
  const float* Wv = (const float*)d_in[8];
  const float* bv = (const float*)d_in[9];
  const float* Wo = (const float*)d_in[10];
  const float* bo = (const float*)d_in[11];
  float* out = (float*)d_out;

  char* ws = (char*)d_ws;
  // region 1 [0, 18874368): qb/kb/vb during projections; O/L after (overlay)
  bf16* qb   = (bf16*)(ws);
  bf16* kb   = (bf16*)(ws + 6291456);
  bf16* vb   = (bf16*)(ws + 12582912);
  bf16* O0   = (bf16*)(ws);              // 24*2048*64 bf16
  bf16* O1   = (bf16*)(ws + 6291456);    // 24*1536*64
  bf16* O2   = (bf16*)(ws + 11010048);   // 24*1024*64
  bf16* O3   = (bf16*)(ws + 14155776);   // 24*512*64
  float* L0  = (float*)(ws + 15728640);  // 24*2048 f32
  float* L1  = (float*)(ws + 15925248);
  float* L2  = (float*)(ws + 16072704);
  float* L3  = (float*)(ws + 16171008);
  // region 2: weights + head tensors
  bf16* wtq  = (bf16*)(ws + 18874368);
  bf16* wtk  = (bf16*)(ws + 20054016);
  bf16* wtv  = (bf16*)(ws + 21233664);
  bf16* wto  = (bf16*)(ws + 22413312);
  bf16* Qh   = (bf16*)(ws + 23592960);
  bf16* Kh   = (bf16*)(ws + 29884416);
  bf16* Vtb  = (bf16*)(ws + 36175872);   // ends 42467328 (~40.5 MB)

  prep_kernel<<<dim3(6912), 256, 0, stream>>>(query, key, value, qb, kb, vb,
                                              Wq, Wk, Wv, Wo, wtq, wtk, wtv, wto);
  gemm_qkv_kernel<<<dim3(576), 256, 0, stream>>>(qb, kb, vb, wtq, wtk, wtv, bq, bk, bv, Qh, Kh, Vtb);
  attn_kernel<<<dim3(960), 256, 0, stream>>>(Qh, Kh, Vtb, O0, O1, O2, O3, L0, L1, L2, L3);
  gemm_out_kernel<<<dim3(384), 256, 0, stream>>>(O0, O1, O2, O3, L0, L1, L2, L3, wto, bo, out);
}